// Round 8
// baseline (1127.704 us; speedup 1.0000x reference)
//
#include <hip/hip_runtime.h>

#define NB 4
#define NH 1024
#define NW 1024
#define NHW (NH * NW)

#define TS 64          // owned output tile side
#define HP 16          // halo
#define SRCS 96        // source region side = TS + 2*HP
#define SRC_PX (SRCS * SRCS)   // 9216
#define TILE_PX (TS * TS)      // 4096

__device__ __forceinline__ float srgb2lin(float v) {
    return v > 0.04045f ? powf((v + 0.055f) * (1.0f / 1.055f), 2.4f) : v * (1.0f / 12.92f);
}

__device__ __forceinline__ float labf(float t) {
    return t > 0.008856f ? cbrtf(t) : 7.787f * t + 4.0f / 29.0f;
}

// Compute Lab for both images, INTERLEAVED (hw,3) output for gather locality.
__global__ void lab_kernel(const float* __restrict__ I0, const float* __restrict__ I1,
                           float* __restrict__ lab0, float* __restrict__ lab1) {
    int idx = blockIdx.x * blockDim.x + threadIdx.x;
    const int total = 2 * NB * NHW;
    if (idx >= total) return;
    int img = (idx >= NB * NHW) ? 1 : 0;
    int p = idx - img * NB * NHW;
    int b = p / NHW;
    int hw = p - b * NHW;
    const float* src = (img ? I1 : I0) + (size_t)b * 3 * NHW + hw;
    float* dst = (img ? lab1 : lab0) + ((size_t)b * NHW + hw) * 3;

    float r = srgb2lin(src[0]);
    float g = srgb2lin(src[NHW]);
    float bl = srgb2lin(src[2 * NHW]);

    float X = (0.412453f * r + 0.35758f * g + 0.180423f * bl) * (1.0f / 0.95047f);
    float Y = (0.212671f * r + 0.71516f * g + 0.072169f * bl);
    float Z = (0.019334f * r + 0.119193f * g + 0.950227f * bl) * (1.0f / 1.08883f);

    float fx = labf(X);
    float fy = labf(Y);
    float fz = labf(Z);

    dst[0] = 116.0f * fy - 16.0f;
    dst[1] = 500.0f * (fx - fy);
    dst[2] = 200.0f * (fy - fz);
}

// z-metric + exp + premultiply, both directions in one launch (z in [0,2*NB)).
// Output pm = {img.r*w, img.g*w, img.b*w, w} interleaved float4 — the ONLY
// per-pixel payload the splat needs besides flow.
__global__ __launch_bounds__(256) void wmap_kernel(
        const float* __restrict__ lab0, const float* __restrict__ lab1,
        const float* __restrict__ I0, const float* __restrict__ I1,
        const float* __restrict__ f01, const float* __restrict__ f10,
        float4* __restrict__ pm0, float4* __restrict__ pm1) {
    const int z = blockIdx.z;
    const int dir = z >> 2;            // NB == 4
    const int b = z & (NB - 1);
    const int tx = threadIdx.x & 31;
    const int ty = threadIdx.x >> 5;
    const int x = blockIdx.x * 32 + tx;
    const int y = blockIdx.y * 8 + ty;
    const int hw = y * NW + x;

    const float* la  = (dir ? lab1 : lab0) + (size_t)b * NHW * 3;
    const float* lb  = (dir ? lab0 : lab1) + (size_t)b * NHW * 3;
    const float* img = (dir ? I1 : I0) + (size_t)b * 3 * NHW;
    const float* fb  = (dir ? f10 : f01) + (size_t)b * 2 * NHW;
    float4* pm = (dir ? pm1 : pm0) + (size_t)b * NHW;

    const float fy_d = fb[hw];
    const float fx_d = fb[NHW + hw];

    float base_y = -1.0f + 2.0f * (float)y / (float)(NH - 1);
    float base_x = -1.0f + 2.0f * (float)x / (float)(NW - 1);
    float gy = 2.0f * fy_d / (float)NH + base_y;
    float gx = 2.0f * fx_d / (float)NW + base_x;
    float ys = fminf(fmaxf(((gy + 1.0f) * (float)NH - 1.0f) * 0.5f, 0.0f), (float)(NH - 1));
    float xs = fminf(fmaxf(((gx + 1.0f) * (float)NW - 1.0f) * 0.5f, 0.0f), (float)(NW - 1));
    float y0f = floorf(ys), x0f = floorf(xs);
    int y0 = (int)y0f, x0 = (int)x0f;
    int y1 = min(y0 + 1, NH - 1), x1 = min(x0 + 1, NW - 1);
    float wy = ys - y0f, wx = xs - x0f;

    const float* p00 = lb + (size_t)(y0 * NW + x0) * 3;
    const float* p01 = lb + (size_t)(y0 * NW + x1) * 3;
    const float* p10 = lb + (size_t)(y1 * NW + x0) * 3;
    const float* p11 = lb + (size_t)(y1 * NW + x1) * 3;
    const float* pa  = la + (size_t)hw * 3;

    float ss = 0.0f;
#pragma unroll
    for (int c = 0; c < 3; ++c) {
        float top = p00[c] * (1.0f - wx) + p01[c] * wx;
        float bot = p10[c] * (1.0f - wx) + p11[c] * wx;
        float v = top * (1.0f - wy) + bot * wy;
        float d = pa[c] - v;
        ss += d * d;
    }
    float w = expf(-0.1f * sqrtf(ss));

    pm[hw] = make_float4(img[hw] * w, img[NHW + hw] * w, img[2 * NHW + hw] * w, w);
}

// Ownership splat, both directions in one launch (z in [0,2*NB)).
// Block owns a 64x64 OUTPUT tile; reads its 96x96 source region (redundancy
// 2.25x vs 4x at 32/16). LDS accumulate (planar, conflict-free) for taps in
// own tile; global-atomic fallback only for taps >HP px displaced whose
// source this block uniquely owns (~9% of px). Flush = 4 coalesced
// atomics/px.
__global__ __launch_bounds__(1024, 2) void splat_own_kernel(
        const float4* __restrict__ pm0, const float4* __restrict__ pm1,
        const float* __restrict__ f01, const float* __restrict__ f10,
        float* __restrict__ acc3_0, float* __restrict__ acc3_1,
        float* __restrict__ w0p, float* __restrict__ w1p) {
    __shared__ float acc[4][TILE_PX];   // 64 KB planar

    const int t = threadIdx.x;
    const int z = blockIdx.z;
    const int dir = z >> 2;
    const int b = z & (NB - 1);
    const int tx0 = blockIdx.x * TS;
    const int ty0 = blockIdx.y * TS;
    const int ox = tx0 - HP;
    const int oy = ty0 - HP;

#pragma unroll
    for (int c = 0; c < 4; ++c)
        for (int i = t; i < TILE_PX; i += 1024) acc[c][i] = 0.0f;
    __syncthreads();

    const float4* pm = (dir ? pm1 : pm0) + (size_t)b * NHW;
    const float* fb  = (dir ? f10 : f01) + (size_t)b * 2 * NHW;
    float* a3 = (dir ? acc3_1 : acc3_0) + (size_t)b * NHW * 3;
    float* wv = (dir ? w1p : w0p) + (size_t)b * NHW;

#pragma unroll
    for (int kk = 0; kk < 9; ++kk) {
        const int i = t + kk * 1024;   // SRC_PX == 9 * 1024 exactly
        const int ry = i / SRCS;
        const int rx = i - ry * SRCS;
        const int sx = ox + rx;
        const int sy = oy + ry;
        if (sx < 0 || sx >= NW || sy < 0 || sy >= NH) continue;
        const int hw = sy * NW + sx;

        const float fy_d = fb[hw];
        const float fx_d = fb[NHW + hw];
        const float4 p4 = pm[hw];

        const float px = fx_d + (float)sx;
        const float py = fy_d + (float)sy;
        const int ix0 = (int)floorf(px);
        const int iy0 = (int)floorf(py);

        const bool interior = (sx >= tx0) && (sx < tx0 + TS) && (sy >= ty0) && (sy < ty0 + TS);

#pragma unroll
        for (int dy = 0; dy < 2; ++dy) {
            const int yi = iy0 + dy;
            if (yi < 0 || yi >= NH) continue;
            const float wgy = 1.0f - fabsf(py - (float)yi);
#pragma unroll
            for (int dx = 0; dx < 2; ++dx) {
                const int xi = ix0 + dx;
                if (xi < 0 || xi >= NW) continue;
                const float wg = wgy * (1.0f - fabsf(px - (float)xi));
                const int lx = xi - tx0;
                const int ly = yi - ty0;
                if (lx >= 0 && lx < TS && ly >= 0 && ly < TS) {
                    const int cell = (ly << 6) + lx;
                    atomicAdd(&acc[0][cell], p4.x * wg);
                    atomicAdd(&acc[1][cell], p4.y * wg);
                    atomicAdd(&acc[2][cell], p4.z * wg);
                    atomicAdd(&acc[3][cell], p4.w * wg);
                } else if (interior) {
                    const int ttx0 = xi & ~(TS - 1);
                    const int tty0 = yi & ~(TS - 1);
                    const bool covered = (sx >= ttx0 - HP) && (sx < ttx0 + TS + HP) &&
                                         (sy >= tty0 - HP) && (sy < tty0 + TS + HP);
                    if (!covered) {
                        const int o = yi * NW + xi;
                        float* p = a3 + (size_t)o * 3;
                        atomicAdd(p + 0, p4.x * wg);
                        atomicAdd(p + 1, p4.y * wg);
                        atomicAdd(p + 2, p4.z * wg);
                        atomicAdd(wv + o, p4.w * wg);
                    }
                }
            }
        }
    }
    __syncthreads();

    // ---- flush own tile: 4 coalesced global atomics per pixel ----
#pragma unroll
    for (int i = t; i < TILE_PX; i += 1024) {
        const int lx = i & (TS - 1);
        const int ly = i >> 6;
        const float v3 = acc[3][i];
        if (v3 == 0.0f) continue;   // exact: img in [0,1] => channels <= w
        const int o = (ty0 + ly) * NW + (tx0 + lx);
        float* p = a3 + (size_t)o * 3;
        atomicAdd(p + 0, acc[0][i]);
        atomicAdd(p + 1, acc[1][i]);
        atomicAdd(p + 2, acc[2][i]);
        atomicAdd(wv + o, v3);
    }
}

// Fused: erode (min, +inf pad) -> dilate (max, -inf pad) of both occupancy masks
// + final blend + output store. LDS-staged separately for both directions.
// Staged path covers p<=8 (k<=17); brute-force global path beyond.
__global__ __launch_bounds__(256) void morph_compose_kernel(
        const float* __restrict__ acc3_0, const float* __restrict__ acc3_1,
        const float* __restrict__ w0p, const float* __restrict__ w1p,
        float* __restrict__ out, const int* __restrict__ kptr) {
    __shared__ float occA[64 * 64], occB[64 * 64];
    __shared__ float erA[48 * 48], erB[48 * 48];

    const int t = threadIdx.x;
    const int b = blockIdx.z;
    const int x0 = blockIdx.x * 32;
    const int y0 = blockIdx.y * 32;
    const int k = *kptr;
    const int p = k >> 1;

    const float* wa = w0p + (size_t)b * NHW;
    const float* wb = w1p + (size_t)b * NHW;

    float mA[4], mB[4];

    if (p <= 8) {
        const int OS = 32 + 4 * p;
        const int ES = 32 + 2 * p;
        for (int i = t; i < OS * OS; i += 256) {
            int sx = x0 - 2 * p + (i % OS);
            int sy = y0 - 2 * p + (i / OS);
            float oa = 1.0f, ob = 1.0f;   // +inf pad for erode == treat OOB as occupied
            if (sx >= 0 && sx < NW && sy >= 0 && sy < NH) {
                oa = (wa[sy * NW + sx] != 0.0f) ? 1.0f : 0.0f;
                ob = (wb[sy * NW + sx] != 0.0f) ? 1.0f : 0.0f;
            }
            occA[i] = oa; occB[i] = ob;
        }
        __syncthreads();
        for (int i = t; i < ES * ES; i += 256) {
            int lx = i % ES, ly = i / ES;
            int ex = x0 - p + lx, ey = y0 - p + ly;
            float ea = 0.0f, eb = 0.0f;   // -inf pad for dilate == 0 (er in {0,1})
            if (ex >= 0 && ex < NW && ey >= 0 && ey < NH) {
                ea = 1.0f; eb = 1.0f;
                for (int dy = -p; dy <= p; ++dy)
                    for (int dx = -p; dx <= p; ++dx) {
                        int oi = (ly + p + dy) * OS + (lx + p + dx);
                        ea = fminf(ea, occA[oi]);
                        eb = fminf(eb, occB[oi]);
                    }
            }
            erA[i] = ea; erB[i] = eb;
        }
        __syncthreads();
#pragma unroll
        for (int r = 0; r < 4; ++r) {
            int lx = t & 31, ly = (t >> 5) + r * 8;
            float ma = 0.0f, mb = 0.0f;
            for (int dy = -p; dy <= p; ++dy)
                for (int dx = -p; dx <= p; ++dx) {
                    int ei = (ly + p + dy) * ES + (lx + p + dx);
                    ma = fmaxf(ma, erA[ei]);
                    mb = fmaxf(mb, erB[ei]);
                }
            mA[r] = ma; mB[r] = mb;
        }
    } else {
        // brute-force fallback, never taken for k<=17; correctness insurance
#pragma unroll
        for (int r = 0; r < 4; ++r) {
            int x = x0 + (t & 31), y = y0 + (t >> 5) + r * 8;
            float ma = 0.0f, mb = 0.0f;
            for (int dy2 = -p; dy2 <= p; ++dy2) {
                int qy = y + dy2; if (qy < 0 || qy >= NH) continue;
                for (int dx2 = -p; dx2 <= p; ++dx2) {
                    int qx = x + dx2; if (qx < 0 || qx >= NW) continue;
                    if (ma >= 1.0f && mb >= 1.0f) break;
                    float ea = 1.0f, eb = 1.0f;
                    for (int dy = -p; dy <= p; ++dy) {
                        int yy = qy + dy; if (yy < 0 || yy >= NH) continue;
                        for (int dx = -p; dx <= p; ++dx) {
                            int xx = qx + dx; if (xx < 0 || xx >= NW) continue;
                            if (wa[yy * NW + xx] == 0.0f) ea = 0.0f;
                            if (wb[yy * NW + xx] == 0.0f) eb = 0.0f;
                        }
                    }
                    ma = fmaxf(ma, ea);
                    mb = fmaxf(mb, eb);
                }
            }
            mA[r] = ma; mB[r] = mb;
        }
    }

    const float* a0 = acc3_0 + (size_t)b * NHW * 3;
    const float* a1 = acc3_1 + (size_t)b * NHW * 3;
    float* o0 = out + (size_t)b * 4 * NHW;
    float* o1 = out + (size_t)NB * 4 * NHW + (size_t)b * 4 * NHW;

#pragma unroll
    for (int r = 0; r < 4; ++r) {
        int lx = t & 31, ly = (t >> 5) + r * 8;
        int x = x0 + lx, y = y0 + ly;
        int hw = y * NW + x;
        float n0 = wa[hw];
        float n1 = wb[hw];
        float d0 = (n0 == 0.0f) ? 1.0f : n0;
        float d1 = (n1 == 0.0f) ? 1.0f : n1;
        const float* c0p = a0 + (size_t)hw * 3;
        const float* c1p = a1 + (size_t)hw * 3;
        float m0 = mA[r], m1 = mB[r];
#pragma unroll
        for (int c = 0; c < 3; ++c) {
            float w0c = c0p[c] / d0;
            float w1c = c1p[c] / d1;
            o0[c * NHW + hw] = m0 * w0c + (1.0f - m0) * w1c;
            o1[c * NHW + hw] = m1 * w1c + (1.0f - m1) * w0c;
        }
        o0[3 * NHW + hw] = m0;
        o1[3 * NHW + hw] = m1;
    }
}

extern "C" void kernel_launch(void* const* d_in, const int* in_sizes, int n_in,
                              void* d_out, int out_size, void* d_ws, size_t ws_size,
                              hipStream_t stream) {
    const float* I0  = (const float*)d_in[0];
    const float* I1  = (const float*)d_in[1];
    const float* f01 = (const float*)d_in[2];
    const float* f10 = (const float*)d_in[3];
    const int*  kptr = (const int*)d_in[4];

    float* ws = (float*)d_ws;
    const size_t n = (size_t)NB * NHW;
    // Layout (16n floats total, same footprint as the round-1 kernel that
    // passed). lab is DEAD after wmap; acc3 overlays it (memset after wmap).
    float* lab0   = ws;                      // [0, 3n)
    float* lab1   = ws + 3 * n;              // [3n, 6n)
    float4* pm0   = (float4*)(ws + 6 * n);   // [6n, 10n)
    float4* pm1   = (float4*)(ws + 10 * n);  // [10n, 14n)
    float* acc3_0 = ws;                      // [0, 3n)   overlays lab0
    float* acc3_1 = ws + 3 * n;              // [3n, 6n)  overlays lab1
    float* w0     = ws + 14 * n;             // [14n, 15n)
    float* w1     = ws + 15 * n;             // [15n, 16n)

    const int T = 256;
    int gLab = (2 * NB * NHW + T - 1) / T;
    dim3 gW(NW / 32, NH / 8, 2 * NB);
    dim3 gTile(NW / TS, NH / TS, 2 * NB);
    dim3 gCmp(NW / 32, NH / 32, NB);

    lab_kernel<<<gLab, T, 0, stream>>>(I0, I1, lab0, lab1);
    wmap_kernel<<<gW, T, 0, stream>>>(lab0, lab1, I0, I1, f01, f10, pm0, pm1);
    hipMemsetAsync(acc3_0, 0, 6 * n * sizeof(float), stream);   // acc3_0 + acc3_1 (over dead lab)
    hipMemsetAsync(w0, 0, 2 * n * sizeof(float), stream);       // w0 + w1
    splat_own_kernel<<<gTile, 1024, 0, stream>>>(pm0, pm1, f01, f10, acc3_0, acc3_1, w0, w1);
    morph_compose_kernel<<<gCmp, T, 0, stream>>>(acc3_0, acc3_1, w0, w1, (float*)d_out, kptr);
}

// Round 9
// 1087.919 us; speedup vs baseline: 1.0366x; 1.0366x over previous
//
#include <hip/hip_runtime.h>

#define NB 4
#define NH 1024
#define NW 1024
#define NHW (NH * NW)

#define TS 32          // owned output tile side
#define HP 16          // halo
#define SRCS 64        // source region side = TS + 2*HP
#define SRC_PX (SRCS * SRCS)   // 4096
#define TILE_PX (TS * TS)      // 1024

__device__ __forceinline__ float srgb2lin(float v) {
    return v > 0.04045f ? powf((v + 0.055f) * (1.0f / 1.055f), 2.4f) : v * (1.0f / 12.92f);
}

__device__ __forceinline__ float labf(float t) {
    return t > 0.008856f ? cbrtf(t) : 7.787f * t + 4.0f / 29.0f;
}

// Compute Lab for both images, INTERLEAVED (hw,3) output for gather locality.
__global__ void lab_kernel(const float* __restrict__ I0, const float* __restrict__ I1,
                           float* __restrict__ lab0, float* __restrict__ lab1) {
    int idx = blockIdx.x * blockDim.x + threadIdx.x;
    const int total = 2 * NB * NHW;
    if (idx >= total) return;
    int img = (idx >= NB * NHW) ? 1 : 0;
    int p = idx - img * NB * NHW;
    int b = p / NHW;
    int hw = p - b * NHW;
    const float* src = (img ? I1 : I0) + (size_t)b * 3 * NHW + hw;
    float* dst = (img ? lab1 : lab0) + ((size_t)b * NHW + hw) * 3;

    float r = srgb2lin(src[0]);
    float g = srgb2lin(src[NHW]);
    float bl = srgb2lin(src[2 * NHW]);

    float X = (0.412453f * r + 0.35758f * g + 0.180423f * bl) * (1.0f / 0.95047f);
    float Y = (0.212671f * r + 0.71516f * g + 0.072169f * bl);
    float Z = (0.019334f * r + 0.119193f * g + 0.950227f * bl) * (1.0f / 1.08883f);

    float fx = labf(X);
    float fy = labf(Y);
    float fz = labf(Z);

    dst[0] = 116.0f * fy - 16.0f;
    dst[1] = 500.0f * (fx - fy);
    dst[2] = 200.0f * (fy - fz);
}

// z-metric + exp + premultiply, both directions in one launch (z in [0,2*NB)).
// Output pm = {img.r*w, img.g*w, img.b*w, w} interleaved float4 — the ONLY
// per-pixel payload the splat needs besides flow.
__global__ __launch_bounds__(256) void wmap_kernel(
        const float* __restrict__ lab0, const float* __restrict__ lab1,
        const float* __restrict__ I0, const float* __restrict__ I1,
        const float* __restrict__ f01, const float* __restrict__ f10,
        float4* __restrict__ pm0, float4* __restrict__ pm1) {
    const int z = blockIdx.z;
    const int dir = z >> 2;            // NB == 4
    const int b = z & (NB - 1);
    const int tx = threadIdx.x & 31;
    const int ty = threadIdx.x >> 5;
    const int x = blockIdx.x * 32 + tx;
    const int y = blockIdx.y * 8 + ty;
    const int hw = y * NW + x;

    const float* la  = (dir ? lab1 : lab0) + (size_t)b * NHW * 3;
    const float* lb  = (dir ? lab0 : lab1) + (size_t)b * NHW * 3;
    const float* img = (dir ? I1 : I0) + (size_t)b * 3 * NHW;
    const float* fb  = (dir ? f10 : f01) + (size_t)b * 2 * NHW;
    float4* pm = (dir ? pm1 : pm0) + (size_t)b * NHW;

    const float fy_d = fb[hw];
    const float fx_d = fb[NHW + hw];

    float base_y = -1.0f + 2.0f * (float)y / (float)(NH - 1);
    float base_x = -1.0f + 2.0f * (float)x / (float)(NW - 1);
    float gy = 2.0f * fy_d / (float)NH + base_y;
    float gx = 2.0f * fx_d / (float)NW + base_x;
    float ys = fminf(fmaxf(((gy + 1.0f) * (float)NH - 1.0f) * 0.5f, 0.0f), (float)(NH - 1));
    float xs = fminf(fmaxf(((gx + 1.0f) * (float)NW - 1.0f) * 0.5f, 0.0f), (float)(NW - 1));
    float y0f = floorf(ys), x0f = floorf(xs);
    int y0 = (int)y0f, x0 = (int)x0f;
    int y1 = min(y0 + 1, NH - 1), x1 = min(x0 + 1, NW - 1);
    float wy = ys - y0f, wx = xs - x0f;

    const float* p00 = lb + (size_t)(y0 * NW + x0) * 3;
    const float* p01 = lb + (size_t)(y0 * NW + x1) * 3;
    const float* p10 = lb + (size_t)(y1 * NW + x0) * 3;
    const float* p11 = lb + (size_t)(y1 * NW + x1) * 3;
    const float* pa  = la + (size_t)hw * 3;

    float ss = 0.0f;
#pragma unroll
    for (int c = 0; c < 3; ++c) {
        float top = p00[c] * (1.0f - wx) + p01[c] * wx;
        float bot = p10[c] * (1.0f - wx) + p11[c] * wx;
        float v = top * (1.0f - wy) + bot * wy;
        float d = pa[c] - v;
        ss += d * d;
    }
    float w = expf(-0.1f * sqrtf(ss));

    pm[hw] = make_float4(img[hw] * w, img[NHW + hw] * w, img[2 * NHW + hw] * w, w);
}

// Ownership splat, both directions in one launch (z in [0,2*NB)).
// Block owns a 32x32 OUTPUT tile; reads its 64x64 source region with
// power-of-2 indexing (r6 geometry: measured fastest). LDS accumulate
// (planar, conflict-free) for taps in own tile; global-atomic fallback only
// for taps >HP displaced whose source this block uniquely owns (~9%).
// Flush = 4 coalesced atomics/px.
__global__ __launch_bounds__(1024, 2) void splat_own_kernel(
        const float4* __restrict__ pm0, const float4* __restrict__ pm1,
        const float* __restrict__ f01, const float* __restrict__ f10,
        float* __restrict__ acc3_0, float* __restrict__ acc3_1,
        float* __restrict__ w0p, float* __restrict__ w1p) {
    __shared__ float acc[4][TILE_PX];   // 16 KB planar

    const int t = threadIdx.x;
    const int z = blockIdx.z;
    const int dir = z >> 2;
    const int b = z & (NB - 1);
    const int tx0 = blockIdx.x * TS;
    const int ty0 = blockIdx.y * TS;
    const int ox = tx0 - HP;
    const int oy = ty0 - HP;

    acc[0][t] = 0.0f; acc[1][t] = 0.0f; acc[2][t] = 0.0f; acc[3][t] = 0.0f;
    __syncthreads();

    const float4* pm = (dir ? pm1 : pm0) + (size_t)b * NHW;
    const float* fb  = (dir ? f10 : f01) + (size_t)b * 2 * NHW;
    float* a3 = (dir ? acc3_1 : acc3_0) + (size_t)b * NHW * 3;
    float* wv = (dir ? w1p : w0p) + (size_t)b * NHW;

#pragma unroll
    for (int kk = 0; kk < 4; ++kk) {
        const int i = t + kk * 1024;   // SRC_PX == 4 * 1024 exactly
        const int rx = i & (SRCS - 1);
        const int ry = i >> 6;
        const int sx = ox + rx;
        const int sy = oy + ry;
        if (sx < 0 || sx >= NW || sy < 0 || sy >= NH) continue;
        const int hw = sy * NW + sx;

        const float fy_d = fb[hw];
        const float fx_d = fb[NHW + hw];
        const float4 p4 = pm[hw];

        const float px = fx_d + (float)sx;
        const float py = fy_d + (float)sy;
        const int ix0 = (int)floorf(px);
        const int iy0 = (int)floorf(py);

        const bool interior = (sx >= tx0) && (sx < tx0 + TS) && (sy >= ty0) && (sy < ty0 + TS);

#pragma unroll
        for (int dy = 0; dy < 2; ++dy) {
            const int yi = iy0 + dy;
            if (yi < 0 || yi >= NH) continue;
            const float wgy = 1.0f - fabsf(py - (float)yi);
#pragma unroll
            for (int dx = 0; dx < 2; ++dx) {
                const int xi = ix0 + dx;
                if (xi < 0 || xi >= NW) continue;
                const float wg = wgy * (1.0f - fabsf(px - (float)xi));
                const int lx = xi - tx0;
                const int ly = yi - ty0;
                if (lx >= 0 && lx < TS && ly >= 0 && ly < TS) {
                    const int cell = (ly << 5) + lx;
                    atomicAdd(&acc[0][cell], p4.x * wg);
                    atomicAdd(&acc[1][cell], p4.y * wg);
                    atomicAdd(&acc[2][cell], p4.z * wg);
                    atomicAdd(&acc[3][cell], p4.w * wg);
                } else if (interior) {
                    const int ttx0 = xi & ~(TS - 1);
                    const int tty0 = yi & ~(TS - 1);
                    const bool covered = (sx >= ttx0 - HP) && (sx < ttx0 + TS + HP) &&
                                         (sy >= tty0 - HP) && (sy < tty0 + TS + HP);
                    if (!covered) {
                        const int o = yi * NW + xi;
                        float* p = a3 + (size_t)o * 3;
                        atomicAdd(p + 0, p4.x * wg);
                        atomicAdd(p + 1, p4.y * wg);
                        atomicAdd(p + 2, p4.z * wg);
                        atomicAdd(wv + o, p4.w * wg);
                    }
                }
            }
        }
    }
    __syncthreads();

    // ---- flush own tile: 4 coalesced global atomics per pixel ----
    {
        const int lx = t & (TS - 1);
        const int ly = t >> 5;
        const float v3 = acc[3][t];
        if (v3 != 0.0f) {   // exact: img in [0,1] => channels <= w
            const int o = (ty0 + ly) * NW + (tx0 + lx);
            float* p = a3 + (size_t)o * 3;
            atomicAdd(p + 0, acc[0][t]);
            atomicAdd(p + 1, acc[1][t]);
            atomicAdd(p + 2, acc[2][t]);
            atomicAdd(wv + o, v3);
        }
    }
}

// Fused: erode (min, +inf pad) -> dilate (max, -inf pad) of both occupancy masks
// + final blend + output store. LDS-staged separately for both directions.
// Staged path covers p<=8 (k<=17); brute-force global path beyond.
__global__ __launch_bounds__(256) void morph_compose_kernel(
        const float* __restrict__ acc3_0, const float* __restrict__ acc3_1,
        const float* __restrict__ w0p, const float* __restrict__ w1p,
        float* __restrict__ out, const int* __restrict__ kptr) {
    __shared__ float occA[64 * 64], occB[64 * 64];
    __shared__ float erA[48 * 48], erB[48 * 48];

    const int t = threadIdx.x;
    const int b = blockIdx.z;
    const int x0 = blockIdx.x * 32;
    const int y0 = blockIdx.y * 32;
    const int k = *kptr;
    const int p = k >> 1;

    const float* wa = w0p + (size_t)b * NHW;
    const float* wb = w1p + (size_t)b * NHW;

    float mA[4], mB[4];

    if (p <= 8) {
        const int OS = 32 + 4 * p;
        const int ES = 32 + 2 * p;
        for (int i = t; i < OS * OS; i += 256) {
            int sx = x0 - 2 * p + (i % OS);
            int sy = y0 - 2 * p + (i / OS);
            float oa = 1.0f, ob = 1.0f;   // +inf pad for erode == treat OOB as occupied
            if (sx >= 0 && sx < NW && sy >= 0 && sy < NH) {
                oa = (wa[sy * NW + sx] != 0.0f) ? 1.0f : 0.0f;
                ob = (wb[sy * NW + sx] != 0.0f) ? 1.0f : 0.0f;
            }
            occA[i] = oa; occB[i] = ob;
        }
        __syncthreads();
        for (int i = t; i < ES * ES; i += 256) {
            int lx = i % ES, ly = i / ES;
            int ex = x0 - p + lx, ey = y0 - p + ly;
            float ea = 0.0f, eb = 0.0f;   // -inf pad for dilate == 0 (er in {0,1})
            if (ex >= 0 && ex < NW && ey >= 0 && ey < NH) {
                ea = 1.0f; eb = 1.0f;
                for (int dy = -p; dy <= p; ++dy)
                    for (int dx = -p; dx <= p; ++dx) {
                        int oi = (ly + p + dy) * OS + (lx + p + dx);
                        ea = fminf(ea, occA[oi]);
                        eb = fminf(eb, occB[oi]);
                    }
            }
            erA[i] = ea; erB[i] = eb;
        }
        __syncthreads();
#pragma unroll
        for (int r = 0; r < 4; ++r) {
            int lx = t & 31, ly = (t >> 5) + r * 8;
            float ma = 0.0f, mb = 0.0f;
            for (int dy = -p; dy <= p; ++dy)
                for (int dx = -p; dx <= p; ++dx) {
                    int ei = (ly + p + dy) * ES + (lx + p + dx);
                    ma = fmaxf(ma, erA[ei]);
                    mb = fmaxf(mb, erB[ei]);
                }
            mA[r] = ma; mB[r] = mb;
        }
    } else {
        // brute-force fallback, never taken for k<=17; correctness insurance
#pragma unroll
        for (int r = 0; r < 4; ++r) {
            int x = x0 + (t & 31), y = y0 + (t >> 5) + r * 8;
            float ma = 0.0f, mb = 0.0f;
            for (int dy2 = -p; dy2 <= p; ++dy2) {
                int qy = y + dy2; if (qy < 0 || qy >= NH) continue;
                for (int dx2 = -p; dx2 <= p; ++dx2) {
                    int qx = x + dx2; if (qx < 0 || qx >= NW) continue;
                    if (ma >= 1.0f && mb >= 1.0f) break;
                    float ea = 1.0f, eb = 1.0f;
                    for (int dy = -p; dy <= p; ++dy) {
                        int yy = qy + dy; if (yy < 0 || yy >= NH) continue;
                        for (int dx = -p; dx <= p; ++dx) {
                            int xx = qx + dx; if (xx < 0 || xx >= NW) continue;
                            if (wa[yy * NW + xx] == 0.0f) ea = 0.0f;
                            if (wb[yy * NW + xx] == 0.0f) eb = 0.0f;
                        }
                    }
                    ma = fmaxf(ma, ea);
                    mb = fmaxf(mb, eb);
                }
            }
            mA[r] = ma; mB[r] = mb;
        }
    }

    const float* a0 = acc3_0 + (size_t)b * NHW * 3;
    const float* a1 = acc3_1 + (size_t)b * NHW * 3;
    float* o0 = out + (size_t)b * 4 * NHW;
    float* o1 = out + (size_t)NB * 4 * NHW + (size_t)b * 4 * NHW;

#pragma unroll
    for (int r = 0; r < 4; ++r) {
        int lx = t & 31, ly = (t >> 5) + r * 8;
        int x = x0 + lx, y = y0 + ly;
        int hw = y * NW + x;
        float n0 = wa[hw];
        float n1 = wb[hw];
        float d0 = (n0 == 0.0f) ? 1.0f : n0;
        float d1 = (n1 == 0.0f) ? 1.0f : n1;
        const float* c0p = a0 + (size_t)hw * 3;
        const float* c1p = a1 + (size_t)hw * 3;
        float m0 = mA[r], m1 = mB[r];
#pragma unroll
        for (int c = 0; c < 3; ++c) {
            float w0c = c0p[c] / d0;
            float w1c = c1p[c] / d1;
            o0[c * NHW + hw] = m0 * w0c + (1.0f - m0) * w1c;
            o1[c * NHW + hw] = m1 * w1c + (1.0f - m1) * w0c;
        }
        o0[3 * NHW + hw] = m0;
        o1[3 * NHW + hw] = m1;
    }
}

extern "C" void kernel_launch(void* const* d_in, const int* in_sizes, int n_in,
                              void* d_out, int out_size, void* d_ws, size_t ws_size,
                              hipStream_t stream) {
    const float* I0  = (const float*)d_in[0];
    const float* I1  = (const float*)d_in[1];
    const float* f01 = (const float*)d_in[2];
    const float* f10 = (const float*)d_in[3];
    const int*  kptr = (const int*)d_in[4];

    float* ws = (float*)d_ws;
    const size_t n = (size_t)NB * NHW;
    // Layout (16n floats total). lab is DEAD after wmap; acc3 overlays it
    // (memset after wmap).
    float* lab0   = ws;                      // [0, 3n)
    float* lab1   = ws + 3 * n;              // [3n, 6n)
    float4* pm0   = (float4*)(ws + 6 * n);   // [6n, 10n)
    float4* pm1   = (float4*)(ws + 10 * n);  // [10n, 14n)
    float* acc3_0 = ws;                      // [0, 3n)   overlays lab0
    float* acc3_1 = ws + 3 * n;              // [3n, 6n)  overlays lab1
    float* w0     = ws + 14 * n;             // [14n, 15n)
    float* w1     = ws + 15 * n;             // [15n, 16n)

    const int T = 256;
    int gLab = (2 * NB * NHW + T - 1) / T;
    dim3 gW(NW / 32, NH / 8, 2 * NB);
    dim3 gTile(NW / TS, NH / TS, 2 * NB);
    dim3 gCmp(NW / 32, NH / 32, NB);

    lab_kernel<<<gLab, T, 0, stream>>>(I0, I1, lab0, lab1);
    wmap_kernel<<<gW, T, 0, stream>>>(lab0, lab1, I0, I1, f01, f10, pm0, pm1);
    hipMemsetAsync(acc3_0, 0, 6 * n * sizeof(float), stream);   // acc3_0 + acc3_1 (over dead lab)
    hipMemsetAsync(w0, 0, 2 * n * sizeof(float), stream);       // w0 + w1
    splat_own_kernel<<<gTile, 1024, 0, stream>>>(pm0, pm1, f01, f10, acc3_0, acc3_1, w0, w1);
    morph_compose_kernel<<<gCmp, T, 0, stream>>>(acc3_0, acc3_1, w0, w1, (float*)d_out, kptr);
}